// Round 5
// baseline (69766.815 us; speedup 1.0000x reference)
//
#include <hip/hip_runtime.h>

#define SEQ  8192
#define HID  1024
#define NBLK 64
#define WPB  16            // waves per block
#define TPB  (WPB * 64)    // 1024 threads
#define KCH  (HID / 64)    // 16 K-chunks per dot product

// d_ws layout:
//   [0, 16KB)   : slots[2][HID] u64, word = (step_tag<<32)|f32bits(h[j])
//   [16KB, ...) : 8 group counters, u32 each, 256B apart (distinct lines)
#define SLOT_WORDS (2 * HID)
#define NCTR       8
#define CTR_STRIDE 64            // u32 stride between counters = 256B
#define CTR_U32OFF 4096          // byte offset 16384 / 4

__device__ __forceinline__ float sigmoidf_fast(float a) {
    return 1.0f / (1.0f + __expf(-a));
}
__device__ __forceinline__ float tanhf_fast(float a) {
    float t = fabsf(a);
    float e = __expf(-2.0f * t);
    float r = (1.0f - e) / (1.0f + e);
    return copysignf(r, a);
}

__global__ __launch_bounds__(TPB, 4) void gru_persistent(
    const float* __restrict__ inp,   // [SEQ, HID]
    const float* __restrict__ Wih,   // [3*HID, HID]
    const float* __restrict__ Whh,   // [3*HID, HID]
    const float* __restrict__ bih,   // [3*HID]
    const float* __restrict__ bhh,   // [3*HID]
    float* __restrict__ out,         // [SEQ, HID]
    unsigned long long* __restrict__ slots,  // [2][HID]
    unsigned* __restrict__ ctr)              // 8 counters, 256B apart
{
    __shared__ float hbuf[2][HID];   // double-buffered h vector (8 KB)
    const int tid  = threadIdx.x;
    const int wave = tid >> 6;
    const int lane = tid & 63;
    const int j    = blockIdx.x * WPB + wave;  // this wave's output row
    const int grp  = blockIdx.x & (NCTR - 1);  // this block's counter group

    // ---- persistent W_hh rows (j, HID+j, 2*HID+j) in VGPRs: 48 regs/thread ----
    float wr[KCH], wz[KCH], wn[KCH];
    {
        const float* Wr = Whh + (size_t)j * HID;
        const float* Wz = Whh + (size_t)(HID + j) * HID;
        const float* Wn = Whh + (size_t)(2 * HID + j) * HID;
#pragma unroll
        for (int k = 0; k < KCH; ++k) {
            wr[k] = Wr[lane + 64 * k];
            wz[k] = Wz[lane + 64 * k];
            wn[k] = Wn[lane + 64 * k];
        }
    }
    // biases added ONCE, after the 64-lane reduction
    const float bxr = bih[j], bxz = bih[HID + j], bxn = bih[2 * HID + j];
    const float bhr = bhh[j], bhz = bhh[HID + j], bhn = bhh[2 * HID + j];
    const float* Ur = Wih + (size_t)j * HID;
    const float* Uz = Wih + (size_t)(HID + j) * HID;
    const float* Un = Wih + (size_t)(2 * HID + j) * HID;

    // ---- h_0 = 0 ----
    hbuf[0][tid] = 0.0f;             // TPB == HID
    __syncthreads();

    // ---- x-side projection for t=1 (pipelined one step ahead) ----
    float xr = 0.0f, xz = 0.0f, xn = 0.0f;
    {
        const float* x = inp;
#pragma unroll
        for (int k = 0; k < KCH; ++k) {
            float xv = x[lane + 64 * k];
            xr = fmaf(Ur[lane + 64 * k], xv, xr);
            xz = fmaf(Uz[lane + 64 * k], xv, xz);
            xn = fmaf(Un[lane + 64 * k], xv, xn);
        }
#pragma unroll
        for (int m = 32; m >= 1; m >>= 1) {
            xr += __shfl_xor(xr, m, 64);
            xz += __shfl_xor(xz, m, 64);
            xn += __shfl_xor(xn, m, 64);
        }
        xr += bxr; xz += bxz; xn += bxn;
    }

    for (int t = 1; t <= SEQ; ++t) {
        // ---- h-side matvec: h_{t-1} from hbuf[(t-1)&1], weights from VGPRs ----
        const float* hb = hbuf[(t - 1) & 1];
        float hr = 0.0f, hz = 0.0f, hn = 0.0f;
#pragma unroll
        for (int k = 0; k < KCH; ++k) {
            float hv = hb[lane + 64 * k];
            hr = fmaf(wr[k], hv, hr);
            hz = fmaf(wz[k], hv, hz);
            hn = fmaf(wn[k], hv, hn);
        }
#pragma unroll
        for (int m = 32; m >= 1; m >>= 1) {
            hr += __shfl_xor(hr, m, 64);
            hz += __shfl_xor(hz, m, 64);
            hn += __shfl_xor(hn, m, 64);
        }
        hr += bhr; hz += bhz; hn += bhn;

        const float hprev = hb[j];
        const float r = sigmoidf_fast(xr + hr);
        const float z = sigmoidf_fast(xz + hz);
        const float n = tanhf_fast(xn + r * hn);
        const float hnew = (1.0f - z) * n + z * hprev;

        if (t < SEQ) {
            // 1) publish tagged row (relaxed agent store, bypasses local L2)
            if (lane == 0) {
                unsigned long long pub = ((unsigned long long)(unsigned)t << 32)
                                       | (unsigned long long)__float_as_uint(hnew);
                __hip_atomic_store(slots + (t & 1) * HID + j, pub,
                                   __ATOMIC_RELAXED, __HIP_MEMORY_SCOPE_AGENT);
            }
            // 2) confirm THIS wave's store is visible at the coherence point
            asm volatile("s_waitcnt vmcnt(0)" ::: "memory");
            // 3) all 16 waves' stores confirmed before the block's single counter-add
            __syncthreads();
            if (tid == 0) {
                __hip_atomic_fetch_add(ctr + grp * CTR_STRIDE, 1u,
                                       __ATOMIC_RELAXED, __HIP_MEMORY_SCOPE_AGENT);
            }
            if (lane == 0) {
                __builtin_nontemporal_store(hnew, out + (size_t)(t - 1) * HID + j);
            }

            // 4) x-side projection for t+1 (all waves; hides under detect latency)
            {
                const float* x = inp + (size_t)t * HID;
                xr = 0.0f; xz = 0.0f; xn = 0.0f;
#pragma unroll
                for (int k = 0; k < KCH; ++k) {
                    float xv = x[lane + 64 * k];
                    xr = fmaf(Ur[lane + 64 * k], xv, xr);
                    xz = fmaf(Uz[lane + 64 * k], xv, xz);
                    xn = fmaf(Un[lane + 64 * k], xv, xn);
                }
#pragma unroll
                for (int m = 32; m >= 1; m >>= 1) {
                    xr += __shfl_xor(xr, m, 64);
                    xz += __shfl_xor(xz, m, 64);
                    xn += __shfl_xor(xn, m, 64);
                }
                xr += bxr; xz += bxz; xn += bxn;
            }

            // 5) wave0: detect on the 8 counter lines (one load instr/iter),
            //    then a single ILP'd tagged fetch of the whole h_t vector.
            if (wave == 0) {
                const unsigned tgt = (unsigned)(t * (NBLK / NCTR));  // 8 adds/ctr/step
                for (;;) {
                    unsigned c = __hip_atomic_load(
                        ctr + (lane & (NCTR - 1)) * CTR_STRIDE,
                        __ATOMIC_RELAXED, __HIP_MEMORY_SCOPE_AGENT);
                    if (__all(c >= tgt)) break;
                    __builtin_amdgcn_s_sleep(1);
                }
                const unsigned long long* rdp = slots + (t & 1) * HID;
                const unsigned expect = (unsigned)t;
                for (;;) {
                    float v[KCH];
                    bool ok = true;
#pragma unroll
                    for (int k = 0; k < KCH; ++k) {
                        unsigned long long wv = __hip_atomic_load(
                            rdp + lane + 64 * k, __ATOMIC_RELAXED, __HIP_MEMORY_SCOPE_AGENT);
                        ok &= ((unsigned)(wv >> 32) == expect);
                        v[k] = __uint_as_float((unsigned)(wv & 0xffffffffu));
                    }
                    if (__all(ok)) {   // expected to pass on the first try
#pragma unroll
                        for (int k = 0; k < KCH; ++k) hbuf[t & 1][lane + 64 * k] = v[k];
                        break;
                    }
                    __builtin_amdgcn_s_sleep(1);
                }
            }
        } else {
            // final step: nothing to exchange, just write the output row
            if (lane == 0) {
                __builtin_nontemporal_store(hnew, out + (size_t)(t - 1) * HID + j);
            }
        }
        __syncthreads();   // h_t in LDS visible to all waves before next step
    }
}

extern "C" void kernel_launch(void* const* d_in, const int* in_sizes, int n_in,
                              void* d_out, int out_size, void* d_ws, size_t ws_size,
                              hipStream_t stream) {
    const float* inp = (const float*)d_in[0];
    const float* Wih = (const float*)d_in[1];
    const float* Whh = (const float*)d_in[2];
    const float* bih = (const float*)d_in[3];
    const float* bhh = (const float*)d_in[4];
    float* out = (float*)d_out;
    unsigned long long* slots = (unsigned long long*)d_ws;
    unsigned* ctr = (unsigned*)d_ws + CTR_U32OFF;

    // zero slots (16KB) + counters region (covers 0xAA poison; replayed every launch)
    hipMemsetAsync(d_ws, 0, 32768, stream);

    gru_persistent<<<dim3(NBLK), dim3(TPB), 0, stream>>>(
        inp, Wih, Whh, bih, bhh, out, slots, ctr);
}

// Round 6
// 64541.754 us; speedup vs baseline: 1.0810x; 1.0810x over previous
//
#include <hip/hip_runtime.h>

#define SEQ  8192
#define HID  1024
#define NBLK 64
#define WPB  16            // waves per block
#define TPB  (WPB * 64)    // 1024 threads
#define KCH  (HID / 64)    // 16 K-chunks per dot product

// slots: 2 parity planes x 64 block-lines x 16 u64 words (128B = 1 cache line per block)
// word = (step_tag<<32)|f32bits(h[j]);  word index (t&1)*HID + j  with j = blk*16 + wave
#define SLOT_WORDS (2 * HID)

__device__ __forceinline__ float sigmoidf_fast(float a) {
    return 1.0f / (1.0f + __expf(-a));
}
__device__ __forceinline__ float tanhf_fast(float a) {
    float t = fabsf(a);
    float e = __expf(-2.0f * t);
    float r = (1.0f - e) / (1.0f + e);
    return copysignf(r, a);
}

__global__ __launch_bounds__(TPB, 4) void gru_persistent(
    const float* __restrict__ inp,   // [SEQ, HID]
    const float* __restrict__ Wih,   // [3*HID, HID]
    const float* __restrict__ Whh,   // [3*HID, HID]
    const float* __restrict__ bih,   // [3*HID]
    const float* __restrict__ bhh,   // [3*HID]
    float* __restrict__ out,         // [SEQ, HID]
    unsigned long long* __restrict__ slots)  // [2][HID]
{
    __shared__ float hbuf[2][HID];              // double-buffered h vector (8 KB)
    __shared__ unsigned long long hg[WPB];      // per-block publish gather (128 B)
    const int tid  = threadIdx.x;
    const int wave = tid >> 6;
    const int lane = tid & 63;
    const int j    = blockIdx.x * WPB + wave;   // this wave's output row

    // ---- persistent W_hh rows (j, HID+j, 2*HID+j) in VGPRs: 48 regs/thread ----
    float wr[KCH], wz[KCH], wn[KCH];
    {
        const float* Wr = Whh + (size_t)j * HID;
        const float* Wz = Whh + (size_t)(HID + j) * HID;
        const float* Wn = Whh + (size_t)(2 * HID + j) * HID;
#pragma unroll
        for (int k = 0; k < KCH; ++k) {
            wr[k] = Wr[lane + 64 * k];
            wz[k] = Wz[lane + 64 * k];
            wn[k] = Wn[lane + 64 * k];
        }
    }
    // biases added ONCE, after the 64-lane reduction
    const float bxr = bih[j], bxz = bih[HID + j], bxn = bih[2 * HID + j];
    const float bhr = bhh[j], bhz = bhh[HID + j], bhn = bhh[2 * HID + j];
    const float* Ur = Wih + (size_t)j * HID;
    const float* Uz = Wih + (size_t)(HID + j) * HID;
    const float* Un = Wih + (size_t)(2 * HID + j) * HID;

    // ---- h_0 = 0 ----
    hbuf[0][tid] = 0.0f;             // TPB == HID
    __syncthreads();

    // ---- x-side projection for t=1 (pipelined one step ahead) ----
    float xr = 0.0f, xz = 0.0f, xn = 0.0f;
    {
        const float* x = inp;
#pragma unroll
        for (int k = 0; k < KCH; ++k) {
            float xv = x[lane + 64 * k];
            xr = fmaf(Ur[lane + 64 * k], xv, xr);
            xz = fmaf(Uz[lane + 64 * k], xv, xz);
            xn = fmaf(Un[lane + 64 * k], xv, xn);
        }
#pragma unroll
        for (int m = 32; m >= 1; m >>= 1) {
            xr += __shfl_xor(xr, m, 64);
            xz += __shfl_xor(xz, m, 64);
            xn += __shfl_xor(xn, m, 64);
        }
        xr += bxr; xz += bxz; xn += bxn;
    }

    for (int t = 1; t <= SEQ; ++t) {
        // ---- h-side matvec: h_{t-1} from hbuf[(t-1)&1], weights from VGPRs ----
        const float* hb = hbuf[(t - 1) & 1];
        float hr = 0.0f, hz = 0.0f, hn = 0.0f;
#pragma unroll
        for (int k = 0; k < KCH; ++k) {
            float hv = hb[lane + 64 * k];
            hr = fmaf(wr[k], hv, hr);
            hz = fmaf(wz[k], hv, hz);
            hn = fmaf(wn[k], hv, hn);
        }
#pragma unroll
        for (int m = 32; m >= 1; m >>= 1) {
            hr += __shfl_xor(hr, m, 64);
            hz += __shfl_xor(hz, m, 64);
            hn += __shfl_xor(hn, m, 64);
        }
        hr += bhr; hz += bhz; hn += bhn;

        const float hprev = hb[j];
        const float r = sigmoidf_fast(xr + hr);
        const float z = sigmoidf_fast(xz + hz);
        const float n = tanhf_fast(xn + r * hn);
        const float hnew = (1.0f - z) * n + z * hprev;

        if (lane == 0) {
            __builtin_nontemporal_store(hnew, out + (size_t)(t - 1) * HID + j);
        }

        if (t < SEQ) {
            // ---- gather the block's 16 tagged values in LDS ----
            if (lane == 0) {
                hg[wave] = ((unsigned long long)(unsigned)t << 32)
                         | (unsigned long long)__float_as_uint(hnew);
            }
            __syncthreads();   // [A] hg complete

            // ---- publish: ONE coalesced 128B transaction per block ----
            if (wave == 0 && lane < WPB) {
                __hip_atomic_store(slots + (t & 1) * HID + blockIdx.x * WPB + lane,
                                   hg[lane], __ATOMIC_RELAXED, __HIP_MEMORY_SCOPE_AGENT);
            }

            // ---- x-side projection for t+1 (all waves; hides publish visibility) ----
            {
                const float* x = inp + (size_t)t * HID;
                xr = 0.0f; xz = 0.0f; xn = 0.0f;
#pragma unroll
                for (int k = 0; k < KCH; ++k) {
                    float xv = x[lane + 64 * k];
                    xr = fmaf(Ur[lane + 64 * k], xv, xr);
                    xz = fmaf(Uz[lane + 64 * k], xv, xz);
                    xn = fmaf(Un[lane + 64 * k], xv, xn);
                }
#pragma unroll
                for (int m = 32; m >= 1; m >>= 1) {
                    xr += __shfl_xor(xr, m, 64);
                    xz += __shfl_xor(xz, m, 64);
                    xn += __shfl_xor(xn, m, 64);
                }
                xr += bxr; xz += bxz; xn += bxn;
            }

            // ---- wave0 consume: light poll (8B/line, 1 load instr/iter),
            //      then ONE bulk tag-verified 8KB fetch ----
            if (wave == 0) {
                const unsigned long long* rd = slots + (t & 1) * HID;
                const unsigned expect = (unsigned)t;
                // phase 1: one 8B word per block-line, lane l <-> block l
                for (;;) {
                    unsigned long long w0 = __hip_atomic_load(
                        rd + lane * WPB, __ATOMIC_RELAXED, __HIP_MEMORY_SCOPE_AGENT);
                    if (__all((unsigned)(w0 >> 32) == expect)) break;
                    __builtin_amdgcn_s_sleep(2);
                }
                // phase 2: bulk fetch, every word self-verifying (retry covers tears)
                for (;;) {
                    float v[KCH];
                    bool ok = true;
#pragma unroll
                    for (int k = 0; k < KCH; ++k) {
                        unsigned long long wv = __hip_atomic_load(
                            rd + lane + 64 * k, __ATOMIC_RELAXED, __HIP_MEMORY_SCOPE_AGENT);
                        ok &= ((unsigned)(wv >> 32) == expect);
                        v[k] = __uint_as_float((unsigned)(wv & 0xffffffffu));
                    }
                    if (__all(ok)) {
#pragma unroll
                        for (int k = 0; k < KCH; ++k) hbuf[t & 1][lane + 64 * k] = v[k];
                        break;
                    }
                    __builtin_amdgcn_s_sleep(1);
                }
            }
        }
        __syncthreads();   // [B] h_t in LDS visible to all waves before next step
    }
}

extern "C" void kernel_launch(void* const* d_in, const int* in_sizes, int n_in,
                              void* d_out, int out_size, void* d_ws, size_t ws_size,
                              hipStream_t stream) {
    const float* inp = (const float*)d_in[0];
    const float* Wih = (const float*)d_in[1];
    const float* Whh = (const float*)d_in[2];
    const float* bih = (const float*)d_in[3];
    const float* bhh = (const float*)d_in[4];
    float* out = (float*)d_out;
    unsigned long long* slots = (unsigned long long*)d_ws;

    // zero both parity planes (tags monotone from 1; 0xAA poison can't false-match either)
    hipMemsetAsync(slots, 0, SLOT_WORDS * sizeof(unsigned long long), stream);

    gru_persistent<<<dim3(NBLK), dim3(TPB), 0, stream>>>(
        inp, Wih, Whh, bih, bhh, out, slots);
}